// Round 7
// baseline (3306.486 us; speedup 1.0000x reference)
//
#include <hip/hip_runtime.h>
#include <stdint.h>

typedef __bf16 bf16x8_t __attribute__((ext_vector_type(8)));
typedef float  f32x4_t  __attribute__((ext_vector_type(4)));

#define MFMA_BF16(A, Bv, C) __builtin_amdgcn_mfma_f32_16x16x32_bf16((A), (Bv), (C), 0, 0, 0)

static constexpr int BB = 16;      // batch
static constexpr int LL = 1024;    // seq len
static constexpr int DD = 2048;    // input dim
static constexpr int HH = 512;     // hidden
static constexpr int GG = 4 * HH;  // 2048 gate rows
static constexpr int MM = BB * LL; // 16384

// ---- workspace layout (bytes) ----
static constexpr size_t XBF_OFF   = 0;                                    // x bf16 [MM][DD]
static constexpr size_t WIHBF_OFF = XBF_OFF   + (size_t)MM * DD * 2;      // W_ih bf16 [GG][DD]
static constexpr size_t WHHBF_OFF = WIHBF_OFF + (size_t)GG * DD * 2;      // W_hh bf16 [GG][HH]
static constexpr size_t XGBF_OFF  = WHHBF_OFF + (size_t)GG * HH * 2;      // xg bf16 [MM][GG]
static constexpr size_t GARR_OFF  = XGBF_OFF  + (size_t)MM * GG * 2;      // g f32 [MM]
static constexpr size_t PART_OFF  = GARR_OFF  + (size_t)MM * 4;           // partials f32 [BB][8][HH]
static constexpr size_t TBUF_OFF  = PART_OFF  + (size_t)BB * 8 * HH * 4;  // tagged h u32 [2][BB][HH]
static constexpr size_t WS_NEED   = TBUF_OFF  + (size_t)2 * BB * HH * 4;  // ~145.2 MB

__device__ __forceinline__ unsigned short f2bf(float f) {
  union { float f; uint32_t u; } v; v.f = f;
  uint32_t r = v.u + 0x7FFFu + ((v.u >> 16) & 1u);   // RNE
  return (unsigned short)(r >> 16);
}
__device__ __forceinline__ float bf2f(unsigned short s) {
  union { uint32_t u; float f; } v; v.u = ((uint32_t)s) << 16;
  return v.f;
}
__device__ __forceinline__ float sigmoidf_fast(float x) { return 1.f / (1.f + __expf(-x)); }
__device__ __forceinline__ float tanhf_fast(float x) {
  float ax = fabsf(x);
  float e  = __expf(2.f * ax);            // inf ok for large ax
  float t  = 1.f - 2.f / (e + 1.f);       // -> 1 as e -> inf
  return copysignf(t, x);
}
__device__ __forceinline__ void async_cp16(const void* g, void* lds) {
  __builtin_amdgcn_global_load_lds((const __attribute__((address_space(1))) uint32_t*)g,
                                   (__attribute__((address_space(3))) uint32_t*)lds, 16, 0, 0);
}

// ---------------- fp32 -> bf16 convert (vectorized) ----------------
__global__ __launch_bounds__(256) void k_f32_to_bf16(const float* __restrict__ s,
                                                     unsigned short* __restrict__ d, int n4) {
  int i = blockIdx.x * 256 + threadIdx.x;
  int stride = gridDim.x * 256;
  for (; i < n4; i += stride) {
    float4 v = ((const float4*)s)[i];
    ushort4 o;
    o.x = f2bf(v.x); o.y = f2bf(v.y); o.z = f2bf(v.z); o.w = f2bf(v.w);
    ((ushort4*)d)[i] = o;
  }
}

// ---------------- xg = x @ W_ih^T + (b_ih + b_hh), bf16 MFMA ----------------
__global__ __launch_bounds__(256) void k_gemm_xg(const unsigned short* __restrict__ A,
                                                 const unsigned short* __restrict__ Bw,
                                                 const float* __restrict__ b_ih,
                                                 const float* __restrict__ b_hh,
                                                 unsigned short* __restrict__ C) {
  __shared__ __align__(16) unsigned short As[128 * 32];
  __shared__ __align__(16) unsigned short Bs[128 * 32];
  const int bid = blockIdx.x;
  const int bn = bid & 15, bm = bid >> 4;
  const int row0 = bm * 128, col0 = bn * 128;
  const int tid = threadIdx.x;
  const int lane = tid & 63, w = tid >> 6;
  const int wr = w >> 1, wc = w & 1;
  const int l15 = lane & 15, l4 = lane >> 4;

  const f32x4_t z4 = {0.f, 0.f, 0.f, 0.f};
  f32x4_t acc[4][4];
#pragma unroll
  for (int mi = 0; mi < 4; ++mi)
#pragma unroll
    for (int ni = 0; ni < 4; ++ni) acc[mi][ni] = z4;

  const unsigned short* ga = A  + (size_t)(row0 + (tid >> 2)) * DD + (tid & 3) * 8;
  const unsigned short* gb = Bw + (size_t)(col0 + (tid >> 2)) * DD + (tid & 3) * 8;
  unsigned short* asw = As + w * 512;
  unsigned short* bsw = Bs + w * 512;

  for (int k0 = 0; k0 < DD; k0 += 32) {
    async_cp16(ga + k0,           asw);
    async_cp16(ga + k0 + 64 * DD, asw + 2048);
    async_cp16(gb + k0,           bsw);
    async_cp16(gb + k0 + 64 * DD, bsw + 2048);
    __syncthreads();
    bf16x8_t af[4], bfr[4];
#pragma unroll
    for (int mi = 0; mi < 4; ++mi)
      af[mi] = *(const bf16x8_t*)(As + (wr * 64 + mi * 16 + l15) * 32 + l4 * 8);
#pragma unroll
    for (int ni = 0; ni < 4; ++ni)
      bfr[ni] = *(const bf16x8_t*)(Bs + (wc * 64 + ni * 16 + l15) * 32 + l4 * 8);
#pragma unroll
    for (int mi = 0; mi < 4; ++mi)
#pragma unroll
      for (int ni = 0; ni < 4; ++ni)
        acc[mi][ni] = MFMA_BF16(af[mi], bfr[ni], acc[mi][ni]);
    __syncthreads();
  }
#pragma unroll
  for (int ni = 0; ni < 4; ++ni) {
    int col = col0 + wc * 64 + ni * 16 + l15;
    float bias = b_ih[col] + b_hh[col];
#pragma unroll
    for (int mi = 0; mi < 4; ++mi) {
      int rowb = row0 + wr * 64 + mi * 16 + l4 * 4;
#pragma unroll
      for (int r = 0; r < 4; ++r)
        C[(size_t)(rowb + r) * GG + col] = f2bf(acc[mi][ni][r] + bias);
    }
  }
}

// ---------------- LSTM recurrence: batches-as-columns ----------------
// 16 WGs total, one per 32-wide h-slice [S0,S0+32). MFMA N-dim = the 16 batches
// (no broadcast redundancy -> 16x less MFMA work, 16x less weight footprint).
// 16 waves/WG = (gate g, K-quarter kp): A-frags = 32 rows x 128 K = 32 VGPRs.
// Per step: poll+stage all-batch h (tagged u32) -> barA -> 8 MFMAs/wave ->
// f32 partials to LDS -> barB -> reduce over 4 kp + xg + activation (2 transc
// per thread) -> barC -> tail (512 thr): c-update, tanh, publish-first.
__global__ __launch_bounds__(1024, 1) void k_lstm(const unsigned short* __restrict__ Whh,
                                                  const unsigned short* __restrict__ xg,
                                                  float* __restrict__ h_all,
                                                  unsigned int* tbuf) {
  const int wg = blockIdx.x;            // 0..15, h-slice owner
  const int S0 = wg * 32;
  const int tid = threadIdx.x;
  const int lane = tid & 63;
  const int wid = tid >> 6;             // 0..15
  const int g  = wid & 3;               // gate (0=i,1=f,2=g,3=o)
  const int kp = wid >> 2;              // K-quarter
  const int l15 = lane & 15, l4 = lane >> 4;

  // LDS: staged h [batch][k] (padded 536 for bank spread), kp-partials, gates
  __shared__ __align__(16) unsigned short Hb[16][536];
  __shared__ float part[16][2][4][64];  // [wid][rowtile][r][lane]
  __shared__ float gl[4][32][17];       // [gate][j][batch], pad 17

  // A-frag preload: rows g*512+S0+tile*16+l15, K = kp*128+kc*32+l4*8 (32 VGPR)
  f32x4_t wa[2][4];
#pragma unroll
  for (int tile = 0; tile < 2; ++tile) {
    const unsigned short* wrow = Whh + (size_t)(g * HH + S0 + tile * 16 + l15) * HH + kp * 128 + l4 * 8;
#pragma unroll
    for (int kc = 0; kc < 4; ++kc)
      wa[tile][kc] = *(const f32x4_t*)(wrow + kc * 32);
  }
#pragma unroll
  for (int tile = 0; tile < 2; ++tile)
#pragma unroll
    for (int kc = 0; kc < 4; ++kc)
      asm volatile("" : "+v"(wa[tile][kc]));

  // reducer mapping: tid = g_r(2) | tile_r(1) | q(2) | rh(1) | b_r(4)
  const int b_r = tid & 15;
  const int rh = (tid >> 4) & 1;
  const int q  = (tid >> 5) & 3;
  const int tile_r = (tid >> 7) & 1;
  const int g_r = tid >> 8;
  const int j_r = tile_r * 16 + q * 4 + rh * 2;   // this thread's j pair (j_r, j_r+1)
  const uint32_t* xgp32 = (const uint32_t*)(xg + (size_t)(b_r << 10) * GG + g_r * HH + S0 + j_r);

  // tail mapping (tid<512): (b_t, j_t)
  const int b_t = tid >> 5, j_t = tid & 31;
  float c_reg = 0.f;

  const f32x4_t z4 = {0.f, 0.f, 0.f, 0.f};
  uint32_t xcur = xgp32[0];             // xg[t=0] pair

  for (int t = 0; t < LL; ++t) {
    // ---- poll: 8 words (one producer slice) per thread, then stage to LDS ----
    unsigned long long* src = (unsigned long long*)(tbuf + ((t & 1) << 13)) + tid * 4;
    const unsigned long long msk = 0xFFFF0000FFFF0000ull;
    const unsigned long long expv = ((unsigned long long)(unsigned int)t << 16)
                                  | ((unsigned long long)(unsigned int)t << 48);
    unsigned long long v0, v1, v2, v3;
    unsigned int guard = 0;
    for (;;) {
      v0 = __hip_atomic_load(src + 0, __ATOMIC_RELAXED, __HIP_MEMORY_SCOPE_AGENT);
      v1 = __hip_atomic_load(src + 1, __ATOMIC_RELAXED, __HIP_MEMORY_SCOPE_AGENT);
      v2 = __hip_atomic_load(src + 2, __ATOMIC_RELAXED, __HIP_MEMORY_SCOPE_AGENT);
      v3 = __hip_atomic_load(src + 3, __ATOMIC_RELAXED, __HIP_MEMORY_SCOPE_AGENT);
      if (((v0 & msk) == expv) && ((v1 & msk) == expv) &&
          ((v2 & msk) == expv) && ((v3 & msk) == expv)) break;
      if (++guard > (1u << 20)) break;   // failsafe: wrong-answer beats a hang
    }
    {
      uint4 d;
      d.x = (uint32_t)(v0 & 0xFFFFu) | ((uint32_t)(v0 >> 16) & 0xFFFF0000u);
      d.y = (uint32_t)(v1 & 0xFFFFu) | ((uint32_t)(v1 >> 16) & 0xFFFF0000u);
      d.z = (uint32_t)(v2 & 0xFFFFu) | ((uint32_t)(v2 >> 16) & 0xFFFF0000u);
      d.w = (uint32_t)(v3 & 0xFFFFu) | ((uint32_t)(v3 >> 16) & 0xFFFF0000u);
      *(uint4*)&Hb[tid >> 6][(tid & 63) * 8] = d;
    }
    __syncthreads();   // barA

    // ---- issue next step's xg pair (hides under MFMA + barB) ----
    uint32_t xnx = 0;
    if (t + 1 < LL) xnx = xgp32[(size_t)(t + 1) * (GG / 2)];

    // ---- 8 MFMAs: 2 independent chains of 4 (rowtile 0/1) ----
    f32x4_t acc0 = z4, acc1 = z4;
#pragma unroll
    for (int kc = 0; kc < 4; ++kc) {
      bf16x8_t hb = *(const bf16x8_t*)&Hb[l15][kp * 128 + kc * 32 + l4 * 8];
      acc0 = MFMA_BF16(__builtin_bit_cast(bf16x8_t, wa[0][kc]), hb, acc0);
      acc1 = MFMA_BF16(__builtin_bit_cast(bf16x8_t, wa[1][kc]), hb, acc1);
    }
#pragma unroll
    for (int r = 0; r < 4; ++r) {
      part[wid][0][r][lane] = acc0[r];
      part[wid][1][r][lane] = acc1[r];
    }
    __syncthreads();   // barB

    // ---- reduce 4 kp-partials + xg, activate (2 values per thread) ----
    {
      const int li = q * 16 + b_r;
      const int r0 = rh * 2;
      float s0 = 0.f, s1 = 0.f;
#pragma unroll
      for (int kk = 0; kk < 4; ++kk) {
        s0 += part[kk * 4 + g_r][tile_r][r0][li];
        s1 += part[kk * 4 + g_r][tile_r][r0 + 1][li];
      }
      s0 += bf2f((unsigned short)(xcur & 0xFFFFu));
      s1 += bf2f((unsigned short)(xcur >> 16));
      float a0, a1;
      if (g_r == 2) { a0 = tanhf_fast(s0);    a1 = tanhf_fast(s1); }
      else          { a0 = sigmoidf_fast(s0); a1 = sigmoidf_fast(s1); }
      gl[g_r][j_r][b_r]     = a0;
      gl[g_r][j_r + 1][b_r] = a1;
    }
    __syncthreads();   // barC

    // ---- tail (512 threads): c update, publish first, then fp32 output ----
    if (tid < 512) {
      float gi = gl[0][j_t][b_t], gf = gl[1][j_t][b_t];
      float gc = gl[2][j_t][b_t], go = gl[3][j_t][b_t];
      c_reg = gf * c_reg + gi * gc;
      float h = go * tanhf_fast(c_reg);
      unsigned int word = ((unsigned int)(t + 1) << 16) | (unsigned int)f2bf(h);
      unsigned int* dst = tbuf + (((t + 1) & 1) << 13) + (b_t << 9) + S0 + j_t;
      __hip_atomic_store(dst, word, __ATOMIC_RELAXED, __HIP_MEMORY_SCOPE_AGENT);
      h_all[(size_t)((b_t << 10) + t) * HH + S0 + j_t] = h;
    }

    xcur = xnx;   // consume prefetch (waitcnt lands here, ~a full phase after issue)
  }
}

// ---------------- g = argmax(logits) as float ----------------
__global__ __launch_bounds__(256) void k_gsel(const float* __restrict__ h, const float* __restrict__ Wlin,
                                              const float* __restrict__ blin, float* __restrict__ g) {
  const int lane = threadIdx.x & 63, w = threadIdx.x >> 6;
  const int idx = blockIdx.x * 4 + w;
  const float4* hp = (const float4*)(h + (size_t)idx * HH + lane * 8);
  const float4* w0 = (const float4*)(Wlin + lane * 8);
  const float4* w1 = (const float4*)(Wlin + HH + lane * 8);
  float4 h0 = hp[0], h1 = hp[1];
  float4 a0 = w0[0], a1 = w0[1], c0 = w1[0], c1 = w1[1];
  float s0 = h0.x*a0.x + h0.y*a0.y + h0.z*a0.z + h0.w*a0.w
           + h1.x*a1.x + h1.y*a1.y + h1.z*a1.z + h1.w*a1.w;
  float s1 = h0.x*c0.x + h0.y*c0.y + h0.z*c0.z + h0.w*c0.w
           + h1.x*c1.x + h1.y*c1.y + h1.z*c1.z + h1.w*c1.w;
#pragma unroll
  for (int off = 32; off > 0; off >>= 1) {
    s0 += __shfl_xor(s0, off);
    s1 += __shfl_xor(s1, off);
  }
  if (lane == 0) g[idx] = (s1 + blin[1] > s0 + blin[0]) ? 1.f : 0.f;
}

// ---------------- scan phase A: per-(b,seg,k) partial sums of g*h ----------------
__global__ __launch_bounds__(256) void k_scan_a(const float* __restrict__ h, const float* __restrict__ g,
                                                float* __restrict__ part) {
  const int bid = blockIdx.x;
  const int b = bid >> 4, seg = (bid >> 1) & 7, kc = bid & 1;
  const int k = kc * 256 + threadIdx.x;
  __shared__ float gs[128];
  if (threadIdx.x < 128) gs[threadIdx.x] = g[b * LL + seg * 128 + threadIdx.x];
  __syncthreads();
  const float* hp = h + ((size_t)(b * LL + seg * 128)) * HH + k;
  float sum = 0.f;
#pragma unroll 4
  for (int l = 0; l < 128; ++l) sum += gs[l] * hp[(size_t)l * HH];
  part[(b * 8 + seg) * HH + k] = sum;
}

// ---------------- scan phase B: emit 2h + fa*S_excl + ba*(S_tot - S_incl) ----------------
__global__ __launch_bounds__(256) void k_scan_b(float* __restrict__ h, const float* __restrict__ g,
                                                const float* __restrict__ part,
                                                const float* __restrict__ fwd, const float* __restrict__ bwd) {
  const int bid = blockIdx.x;
  const int b = bid >> 4, seg = (bid >> 1) & 7, kc = bid & 1;
  const int k = kc * 256 + threadIdx.x;
  __shared__ float gs[128];
  if (threadIdx.x < 128) gs[threadIdx.x] = g[b * LL + seg * 128 + threadIdx.x];
  __syncthreads();
  float base = 0.f, total = 0.f;
#pragma unroll
  for (int s = 0; s < 8; ++s) {
    float v = part[(b * 8 + s) * HH + k];
    total += v;
    if (s < seg) base += v;
  }
  const float fa = fwd[k], ba = bwd[k];
  float run = base;
  float* hp = h + ((size_t)(b * LL + seg * 128)) * HH + k;
  for (int l = 0; l < 128; ++l) {
    float hv = hp[(size_t)l * HH];
    float term = gs[l] * hv;
    hp[(size_t)l * HH] = 2.f * hv + fa * run + ba * (total - run - term);
    run += term;
  }
}

extern "C" void kernel_launch(void* const* d_in, const int* in_sizes, int n_in,
                              void* d_out, int out_size, void* d_ws, size_t ws_size,
                              hipStream_t stream) {
  if (ws_size < WS_NEED) return;
  const float* x    = (const float*)d_in[0];
  const float* Wih  = (const float*)d_in[1];
  const float* Whh  = (const float*)d_in[2];
  const float* b_ih = (const float*)d_in[3];
  const float* b_hh = (const float*)d_in[4];
  const float* Wlin = (const float*)d_in[5];
  const float* blin = (const float*)d_in[6];
  const float* fwd  = (const float*)d_in[7];
  const float* bwd  = (const float*)d_in[8];
  char* ws = (char*)d_ws;
  unsigned short* xbf   = (unsigned short*)(ws + XBF_OFF);
  unsigned short* wihbf = (unsigned short*)(ws + WIHBF_OFF);
  unsigned short* whhbf = (unsigned short*)(ws + WHHBF_OFF);
  unsigned short* xgbf  = (unsigned short*)(ws + XGBF_OFF);
  float*          garr  = (float*)(ws + GARR_OFF);
  float*          part  = (float*)(ws + PART_OFF);
  unsigned int*   tbuf  = (unsigned int*)(ws + TBUF_OFF);
  float* out = (float*)d_out;

  // zero tagged h buffer: tag 0 == valid h[-1] = 0 (deterministic across graph replays)
  (void)hipMemsetAsync(ws + TBUF_OFF, 0, (size_t)2 * BB * HH * 4, stream);

  k_f32_to_bf16<<<2048, 256, 0, stream>>>(x,   xbf,   MM * DD / 4);
  k_f32_to_bf16<<<1024, 256, 0, stream>>>(Wih, wihbf, GG * DD / 4);
  k_f32_to_bf16<<<256,  256, 0, stream>>>(Whh, whhbf, GG * HH / 4);
  k_gemm_xg<<<(MM / 128) * (GG / 128), 256, 0, stream>>>(xbf, wihbf, b_ih, b_hh, xgbf);
  k_lstm<<<16, 1024, 0, stream>>>(whhbf, xgbf, out, tbuf);
  k_gsel<<<MM / 4, 256, 0, stream>>>(out, Wlin, blin, garr);
  k_scan_a<<<256, 256, 0, stream>>>(out, garr, part);
  k_scan_b<<<256, 256, 0, stream>>>(out, garr, part, fwd, bwd);
}

// Round 8
// 1946.737 us; speedup vs baseline: 1.6985x; 1.6985x over previous
//
#include <hip/hip_runtime.h>
#include <stdint.h>

typedef __bf16 bf16x8_t __attribute__((ext_vector_type(8)));
typedef float  f32x4_t  __attribute__((ext_vector_type(4)));

#define MFMA_BF16(A, Bv, C) __builtin_amdgcn_mfma_f32_16x16x32_bf16((A), (Bv), (C), 0, 0, 0)

static constexpr int BB = 16;      // batch
static constexpr int LL = 1024;    // seq len
static constexpr int DD = 2048;    // input dim
static constexpr int HH = 512;     // hidden
static constexpr int GG = 4 * HH;  // 2048 gate rows
static constexpr int MM = BB * LL; // 16384

// ---- workspace layout (bytes) ----
static constexpr size_t XBF_OFF   = 0;                                    // x bf16 [MM][DD]
static constexpr size_t WIHBF_OFF = XBF_OFF   + (size_t)MM * DD * 2;      // W_ih bf16 [GG][DD]
static constexpr size_t WHHBF_OFF = WIHBF_OFF + (size_t)GG * DD * 2;      // W_hh bf16 [GG][HH]
static constexpr size_t XGBF_OFF  = WHHBF_OFF + (size_t)GG * HH * 2;      // xg bf16 [MM][GG]
static constexpr size_t GARR_OFF  = XGBF_OFF  + (size_t)MM * GG * 2;      // g f32 [MM]
static constexpr size_t PART_OFF  = GARR_OFF  + (size_t)MM * 4;           // partials f32 [BB][8][HH]
static constexpr size_t TBUF_OFF  = PART_OFF  + (size_t)BB * 8 * HH * 4;  // tagged h u32 [2][BB][HH] (MALL path)
static constexpr size_t LBUF_OFF  = TBUF_OFF  + (size_t)2 * BB * HH * 4;  // tagged h u32 [2][BB][HH] (XCD-local path)
static constexpr size_t WS_NEED   = LBUF_OFF  + (size_t)2 * BB * HH * 4;  // ~145.3 MB

__device__ __forceinline__ unsigned short f2bf(float f) {
  union { float f; uint32_t u; } v; v.f = f;
  uint32_t r = v.u + 0x7FFFu + ((v.u >> 16) & 1u);   // RNE
  return (unsigned short)(r >> 16);
}
__device__ __forceinline__ float bf2f(unsigned short s) {
  union { uint32_t u; float f; } v; v.u = ((uint32_t)s) << 16;
  return v.f;
}
__device__ __forceinline__ float sigmoidf_fast(float x) { return 1.f / (1.f + __expf(-x)); }
__device__ __forceinline__ float tanhf_fast(float x) {
  float ax = fabsf(x);
  float e  = __expf(2.f * ax);            // inf ok for large ax
  float t  = 1.f - 2.f / (e + 1.f);       // -> 1 as e -> inf
  return copysignf(t, x);
}
__device__ __forceinline__ void async_cp16(const void* g, void* lds) {
  __builtin_amdgcn_global_load_lds((const __attribute__((address_space(1))) uint32_t*)g,
                                   (__attribute__((address_space(3))) uint32_t*)lds, 16, 0, 0);
}

// ---------------- fp32 -> bf16 convert (vectorized) ----------------
__global__ __launch_bounds__(256) void k_f32_to_bf16(const float* __restrict__ s,
                                                     unsigned short* __restrict__ d, int n4) {
  int i = blockIdx.x * 256 + threadIdx.x;
  int stride = gridDim.x * 256;
  for (; i < n4; i += stride) {
    float4 v = ((const float4*)s)[i];
    ushort4 o;
    o.x = f2bf(v.x); o.y = f2bf(v.y); o.z = f2bf(v.z); o.w = f2bf(v.w);
    ((ushort4*)d)[i] = o;
  }
}

// ---------------- xg = x @ W_ih^T + (b_ih + b_hh), bf16 MFMA ----------------
__global__ __launch_bounds__(256) void k_gemm_xg(const unsigned short* __restrict__ A,
                                                 const unsigned short* __restrict__ Bw,
                                                 const float* __restrict__ b_ih,
                                                 const float* __restrict__ b_hh,
                                                 unsigned short* __restrict__ C) {
  __shared__ __align__(16) unsigned short As[128 * 32];
  __shared__ __align__(16) unsigned short Bs[128 * 32];
  const int bid = blockIdx.x;
  const int bn = bid & 15, bm = bid >> 4;
  const int row0 = bm * 128, col0 = bn * 128;
  const int tid = threadIdx.x;
  const int lane = tid & 63, w = tid >> 6;
  const int wr = w >> 1, wc = w & 1;
  const int l15 = lane & 15, l4 = lane >> 4;

  const f32x4_t z4 = {0.f, 0.f, 0.f, 0.f};
  f32x4_t acc[4][4];
#pragma unroll
  for (int mi = 0; mi < 4; ++mi)
#pragma unroll
    for (int ni = 0; ni < 4; ++ni) acc[mi][ni] = z4;

  const unsigned short* ga = A  + (size_t)(row0 + (tid >> 2)) * DD + (tid & 3) * 8;
  const unsigned short* gb = Bw + (size_t)(col0 + (tid >> 2)) * DD + (tid & 3) * 8;
  unsigned short* asw = As + w * 512;
  unsigned short* bsw = Bs + w * 512;

  for (int k0 = 0; k0 < DD; k0 += 32) {
    async_cp16(ga + k0,           asw);
    async_cp16(ga + k0 + 64 * DD, asw + 2048);
    async_cp16(gb + k0,           bsw);
    async_cp16(gb + k0 + 64 * DD, bsw + 2048);
    __syncthreads();
    bf16x8_t af[4], bfr[4];
#pragma unroll
    for (int mi = 0; mi < 4; ++mi)
      af[mi] = *(const bf16x8_t*)(As + (wr * 64 + mi * 16 + l15) * 32 + l4 * 8);
#pragma unroll
    for (int ni = 0; ni < 4; ++ni)
      bfr[ni] = *(const bf16x8_t*)(Bs + (wc * 64 + ni * 16 + l15) * 32 + l4 * 8);
#pragma unroll
    for (int mi = 0; mi < 4; ++mi)
#pragma unroll
      for (int ni = 0; ni < 4; ++ni)
        acc[mi][ni] = MFMA_BF16(af[mi], bfr[ni], acc[mi][ni]);
    __syncthreads();
  }
#pragma unroll
  for (int ni = 0; ni < 4; ++ni) {
    int col = col0 + wc * 64 + ni * 16 + l15;
    float bias = b_ih[col] + b_hh[col];
#pragma unroll
    for (int mi = 0; mi < 4; ++mi) {
      int rowb = row0 + wr * 64 + mi * 16 + l4 * 4;
#pragma unroll
      for (int r = 0; r < 4; ++r)
        C[(size_t)(rowb + r) * GG + col] = f2bf(acc[mi][ni][r] + bias);
    }
  }
}

// ---------------- LSTM recurrence ----------------
// R5 structure + XCD-local exchange fast path.
// Producers dual-publish each tagged word: plain store -> lbuf (XCD-local L2,
// ~200cyc visible to same-XCD consumers via sc0 loads) AND agent-scope atomic
// store -> tbuf (MALL, the always-correct path). Consumers poll lbuf with
// `global_load_dwordx2 ... sc0` (bypass L1, serve from L2) up to 256 tries,
// then strike + fall back to the MALL poll. 8 strikes -> MALL-only. Correctness
// never depends on WG->XCD placement; the fast path is purely opportunistic
// (bid%8 grouping puts each batch's 16 WGs on one XCD in practice).
__global__ __launch_bounds__(256, 1) void k_lstm(const unsigned short* __restrict__ Whh,
                                                 const unsigned short* __restrict__ xg,
                                                 float* __restrict__ h_all,
                                                 unsigned int* tbuf,
                                                 unsigned int* lbuf) {
  const int bid = blockIdx.x;
  const int b  = (bid & 7) + 8 * (bid >> 7);  // same-XCD grouping heuristic
  const int wg = (bid >> 3) & 15;
  const int tid = threadIdx.x;
  const int lane = tid & 63, w = tid >> 6;    // wave w handles gate w (0=i,1=f,2=g,3=o)
  const int l15 = lane & 15, l4 = lane >> 4;
  const int K0 = wg * 32;

  __shared__ float gl[4][32];                 // activated gates
  __shared__ __align__(16) unsigned short h_lds[HH];

  // preload W_hh fragments: A[row][k], row=lane&15, k=(lane>>4)*8+j
  f32x4_t wfr[2][16];
#pragma unroll
  for (int mi = 0; mi < 2; ++mi) {
    const unsigned short* wrow = Whh + (size_t)(w * HH + K0 + mi * 16 + l15) * HH + l4 * 8;
#pragma unroll
    for (int kt = 0; kt < 16; ++kt)
      wfr[mi][kt] = *(const f32x4_t*)(wrow + kt * 32);
  }
#pragma unroll
  for (int mi = 0; mi < 2; ++mi)
#pragma unroll
    for (int kt = 0; kt < 16; ++kt)
      asm volatile("" : "+v"(wfr[mi][kt]));

  float c_reg = 0.f;
  const f32x4_t z4 = {0.f, 0.f, 0.f, 0.f};

  // distributed-activation lane mapping: lanes l15<8 each own one element
  const bool act_lane = (l15 < 8);
  const int r_sel = l15 & 3;
  const int jj = ((l15 >> 2) << 4) + (l4 << 2) + r_sel;
  const unsigned short* xgp = xg + (size_t)(b << 10) * GG + w * HH + K0 + jj;
  float xcur = 0.f;
  if (act_lane) xcur = bf2f(xgp[0]);          // xg[t=0]

  int strikes = 0;

  for (int t = 0; t < LL; ++t) {
    const unsigned long long msk  = 0xFFFF0000FFFF0000ull;
    const unsigned long long tg   = (unsigned long long)(unsigned int)t;
    const unsigned long long expv = (tg << 16) | (tg << 48);
    unsigned long long v = 0;
    bool got = false;

    // ---- fast path: poll XCD-local copy via sc0 (L2-served, L1-bypassed) ----
    if (strikes < 8) {
      unsigned long long* lsrc = (unsigned long long*)(lbuf + (((t & 1) * BB + b) << 9)) + tid;
      for (int it = 0; it < 256; ++it) {
        unsigned long long lv;
        asm volatile("global_load_dwordx2 %0, %1, off sc0\n\ts_waitcnt vmcnt(0)"
                     : "=v"(lv) : "v"(lsrc));
        if ((lv & msk) == expv) { v = lv; got = true; break; }
      }
      if (!got) ++strikes;
    }
    // ---- fallback: MALL poll (always correct) ----
    if (!got) {
      unsigned long long* src = (unsigned long long*)(tbuf + (((t & 1) * BB + b) << 9)) + tid;
      unsigned int guard = 0;
      for (;;) {
        v = __hip_atomic_load(src, __ATOMIC_RELAXED, __HIP_MEMORY_SCOPE_AGENT);
        if ((v & msk) == expv) break;
        if (++guard > (1u << 20)) break;   // failsafe: wrong-answer beats a hang
      }
    }
    ushort2 hv2; hv2.x = (unsigned short)v; hv2.y = (unsigned short)(v >> 32);
    ((ushort2*)h_lds)[tid] = hv2;
    __syncthreads();

    // ---- issue next step's xg scalar load (act lanes; hides under MFMA) ----
    unsigned short xnx = 0;
    if (act_lane && (t + 1 < LL)) xnx = xgp[(size_t)(t + 1) * GG];

    // ---- gates: 4 independent MFMA chains of 8 ----
    f32x4_t a0a = z4, a0b = z4, a1a = z4, a1b = z4;
#pragma unroll
    for (int kt = 0; kt < 8; ++kt) {
      bf16x8_t hva = *(const bf16x8_t*)(h_lds + kt * 32 + l4 * 8);
      bf16x8_t hvb = *(const bf16x8_t*)(h_lds + (kt + 8) * 32 + l4 * 8);
      a0a = MFMA_BF16(__builtin_bit_cast(bf16x8_t, wfr[0][kt]),     hva, a0a);
      a1a = MFMA_BF16(__builtin_bit_cast(bf16x8_t, wfr[1][kt]),     hva, a1a);
      a0b = MFMA_BF16(__builtin_bit_cast(bf16x8_t, wfr[0][kt + 8]), hvb, a0b);
      a1b = MFMA_BF16(__builtin_bit_cast(bf16x8_t, wfr[1][kt + 8]), hvb, a1b);
    }

    // ---- distributed activation: one transcendental per lane ----
    if (act_lane) {
      f32x4_t s = (l15 >= 4) ? (a1a + a1b) : (a0a + a0b);
      float e01 = (r_sel & 1) ? s[1] : s[0];
      float e23 = (r_sel & 1) ? s[3] : s[2];
      float raw = ((r_sel & 2) ? e23 : e01) + xcur;
      gl[w][jj] = (w == 2) ? tanhf_fast(raw) : sigmoidf_fast(raw);
    }
    __syncthreads();

    // ---- tail (32 threads): c update, dual publish (local first), fp32 out ----
    if (tid < 32) {
      float gi = gl[0][tid], gf = gl[1][tid], gc = gl[2][tid], go = gl[3][tid];
      c_reg = gf * c_reg + gi * gc;
      float h = go * tanhf_fast(c_reg);
      unsigned int word = ((unsigned int)(t + 1) << 16) | (unsigned int)f2bf(h);
      const int off = ((((t + 1) & 1) * BB + b) << 9) + K0 + tid;
      unsigned int* ldst = lbuf + off;
      asm volatile("global_store_dword %0, %1, off" :: "v"(ldst), "v"(word) : "memory");
      __hip_atomic_store(tbuf + off, word, __ATOMIC_RELAXED, __HIP_MEMORY_SCOPE_AGENT);
      h_all[(size_t)((b << 10) + t) * HH + K0 + tid] = h;
    }

    // ---- consume xg[t+1] (after activation used xcur) ----
    if (act_lane) xcur = bf2f(xnx);
  }
}

// ---------------- g = argmax(logits) as float ----------------
__global__ __launch_bounds__(256) void k_gsel(const float* __restrict__ h, const float* __restrict__ Wlin,
                                              const float* __restrict__ blin, float* __restrict__ g) {
  const int lane = threadIdx.x & 63, w = threadIdx.x >> 6;
  const int idx = blockIdx.x * 4 + w;
  const float4* hp = (const float4*)(h + (size_t)idx * HH + lane * 8);
  const float4* w0 = (const float4*)(Wlin + lane * 8);
  const float4* w1 = (const float4*)(Wlin + HH + lane * 8);
  float4 h0 = hp[0], h1 = hp[1];
  float4 a0 = w0[0], a1 = w0[1], c0 = w1[0], c1 = w1[1];
  float s0 = h0.x*a0.x + h0.y*a0.y + h0.z*a0.z + h0.w*a0.w
           + h1.x*a1.x + h1.y*a1.y + h1.z*a1.z + h1.w*a1.w;
  float s1 = h0.x*c0.x + h0.y*c0.y + h0.z*c0.z + h0.w*c0.w
           + h1.x*c1.x + h1.y*c1.y + h1.z*c1.z + h1.w*c1.w;
#pragma unroll
  for (int off = 32; off > 0; off >>= 1) {
    s0 += __shfl_xor(s0, off);
    s1 += __shfl_xor(s1, off);
  }
  if (lane == 0) g[idx] = (s1 + blin[1] > s0 + blin[0]) ? 1.f : 0.f;
}

// ---------------- scan phase A: per-(b,seg,k) partial sums of g*h ----------------
__global__ __launch_bounds__(256) void k_scan_a(const float* __restrict__ h, const float* __restrict__ g,
                                                float* __restrict__ part) {
  const int bid = blockIdx.x;
  const int b = bid >> 4, seg = (bid >> 1) & 7, kc = bid & 1;
  const int k = kc * 256 + threadIdx.x;
  __shared__ float gs[128];
  if (threadIdx.x < 128) gs[threadIdx.x] = g[b * LL + seg * 128 + threadIdx.x];
  __syncthreads();
  const float* hp = h + ((size_t)(b * LL + seg * 128)) * HH + k;
  float sum = 0.f;
#pragma unroll 4
  for (int l = 0; l < 128; ++l) sum += gs[l] * hp[(size_t)l * HH];
  part[(b * 8 + seg) * HH + k] = sum;
}

// ---------------- scan phase B: emit 2h + fa*S_excl + ba*(S_tot - S_incl) ----------------
__global__ __launch_bounds__(256) void k_scan_b(float* __restrict__ h, const float* __restrict__ g,
                                                const float* __restrict__ part,
                                                const float* __restrict__ fwd, const float* __restrict__ bwd) {
  const int bid = blockIdx.x;
  const int b = bid >> 4, seg = (bid >> 1) & 7, kc = bid & 1;
  const int k = kc * 256 + threadIdx.x;
  __shared__ float gs[128];
  if (threadIdx.x < 128) gs[threadIdx.x] = g[b * LL + seg * 128 + threadIdx.x];
  __syncthreads();
  float base = 0.f, total = 0.f;
#pragma unroll
  for (int s = 0; s < 8; ++s) {
    float v = part[(b * 8 + s) * HH + k];
    total += v;
    if (s < seg) base += v;
  }
  const float fa = fwd[k], ba = bwd[k];
  float run = base;
  float* hp = h + ((size_t)(b * LL + seg * 128)) * HH + k;
  for (int l = 0; l < 128; ++l) {
    float hv = hp[(size_t)l * HH];
    float term = gs[l] * hv;
    hp[(size_t)l * HH] = 2.f * hv + fa * run + ba * (total - run - term);
    run += term;
  }
}

extern "C" void kernel_launch(void* const* d_in, const int* in_sizes, int n_in,
                              void* d_out, int out_size, void* d_ws, size_t ws_size,
                              hipStream_t stream) {
  if (ws_size < WS_NEED) return;
  const float* x    = (const float*)d_in[0];
  const float* Wih  = (const float*)d_in[1];
  const float* Whh  = (const float*)d_in[2];
  const float* b_ih = (const float*)d_in[3];
  const float* b_hh = (const float*)d_in[4];
  const float* Wlin = (const float*)d_in[5];
  const float* blin = (const float*)d_in[6];
  const float* fwd  = (const float*)d_in[7];
  const float* bwd  = (const float*)d_in[8];
  char* ws = (char*)d_ws;
  unsigned short* xbf   = (unsigned short*)(ws + XBF_OFF);
  unsigned short* wihbf = (unsigned short*)(ws + WIHBF_OFF);
  unsigned short* whhbf = (unsigned short*)(ws + WHHBF_OFF);
  unsigned short* xgbf  = (unsigned short*)(ws + XGBF_OFF);
  float*          garr  = (float*)(ws + GARR_OFF);
  float*          part  = (float*)(ws + PART_OFF);
  unsigned int*   tbuf  = (unsigned int*)(ws + TBUF_OFF);
  unsigned int*   lbuf  = (unsigned int*)(ws + LBUF_OFF);
  float* out = (float*)d_out;

  // zero both tagged h buffers: tag 0 == valid h[-1] = 0 (deterministic across replays)
  (void)hipMemsetAsync(ws + TBUF_OFF, 0, (size_t)4 * BB * HH * 4, stream);

  k_f32_to_bf16<<<2048, 256, 0, stream>>>(x,   xbf,   MM * DD / 4);
  k_f32_to_bf16<<<1024, 256, 0, stream>>>(Wih, wihbf, GG * DD / 4);
  k_f32_to_bf16<<<256,  256, 0, stream>>>(Whh, whhbf, GG * HH / 4);
  k_gemm_xg<<<(MM / 128) * (GG / 128), 256, 0, stream>>>(xbf, wihbf, b_ih, b_hh, xgbf);
  k_lstm<<<256, 256, 0, stream>>>(whhbf, xgbf, out, tbuf, lbuf);
  k_gsel<<<MM / 4, 256, 0, stream>>>(out, Wlin, blin, garr);
  k_scan_a<<<256, 256, 0, stream>>>(out, garr, part);
  k_scan_b<<<256, 256, 0, stream>>>(out, garr, part, fwd, bwd);
}